// Round 9
// baseline (288.367 us; speedup 1.0000x reference)
//
#include <hip/hip_runtime.h>
#include <math.h>

#define N 256
#define TPAD 33   // transposed x-vector leading pad (bank-spread)

typedef float v2f __attribute__((ext_vector_type(2)));

// xor-swizzle within 32-lane half (DS pipe, 1 instr) — PROVEN primitive
template<int XM>
__device__ __forceinline__ float swz(float v) {
  int i = __builtin_amdgcn_ds_swizzle(__builtin_bit_cast(int, v), (XM << 10) | 0x1F);
  return __builtin_bit_cast(float, i);
}
// DPP lane-shuffle (VALU pipe, not DS)
template<int CTRL>
__device__ __forceinline__ float dppmv(float v) {
  int y = __builtin_amdgcn_update_dpp(0, __builtin_bit_cast(int, v), CTRL, 0xF, 0xF, true);
  return __builtin_bit_cast(float, y);
}
// sum over 32-lane half: 4 VALU rotate-adds + 1 swizzle; all lanes get the sum
__device__ __forceinline__ float red32s(float v) {
  v += dppmv<0x121>(v);   // row_ror:1
  v += dppmv<0x122>(v);   // row_ror:2
  v += dppmv<0x124>(v);   // row_ror:4
  v += dppmv<0x128>(v);   // row_ror:8  -> 16-lane row sum, all lanes
  v += swz<16>(v);        // cross the two 16-rows of the 32-half
  return v;
}

// transposed index for x-vectors: col c lives at (c&7)*TPAD + (c>>3).
__device__ __forceinline__ int txi(int c) { return (c & 7) * TPAD + (c >> 3); }

__global__ __launch_bounds__(1024, 4) void icvp_kernel(
    const float* __restrict__ X, const float* __restrict__ A,
    const float* __restrict__ Bv, float* __restrict__ out)
{
  const int p     = blockIdx.x;
  const int t     = threadIdx.x;
  const int w     = t >> 6;
  const int lane  = t & 63;
  const int h     = lane >> 5;
  const int j     = lane & 31;       // col-block within group
  const int G     = w * 2 + h;       // row-group: owns rows G*8..+8
  const int c_red = t >> 2;          // reducer: column owned (x4 dup over h4)
  const int h4    = t & 3;
  const int chnk  = c_red >> 3;
  const int coff  = c_red & 7;
  const int coffR = coff ^ (((chnk >> 2) & 1) << 2);
  const int rot   = ((j >> 2) & 1) << 2;          // writer slot rotation
  const int cT    = txi(c_red);
  const int tT    = txi(t & (N - 1));

  __shared__ __align__(16) float part[32 * 256];      // [group][swizzled+rotated col]
  __shared__ __align__(16) float xn[8 * TPAD], x0n[8 * TPAD], gn[8 * TPAD];
  __shared__ __align__(16) float wsc[16];
  __shared__ __align__(16) float wsc2[16];
  __shared__ float scal[4];

  // ---- A tile as col-PAIRS: A2[r][q] = (A[row][2q], A[row][2q+1]) ----
  v2f A2[8][4];
  {
    const float* Ap = A + (size_t)p * (N * N) + (G * 8) * N + j * 8;
    #pragma unroll
    for (int r = 0; r < 8; ++r) {
      const float4* src = reinterpret_cast<const float4*>(Ap + r * N);
      float4 a0 = src[0], a1 = src[1];
      A2[r][0] = (v2f){a0.x, a0.y}; A2[r][1] = (v2f){a0.z, a0.w};
      A2[r][2] = (v2f){a1.x, a1.y}; A2[r][3] = (v2f){a1.z, a1.w};
    }
  }
  if (t < N) { float xv = X[p * N + t]; xn[tT] = xv; x0n[tT] = xv; }

  // ---- row norms: EXACT r8 scalar association (c ascending 0..7) ----
  float btl32[8];
  {
    const float4* bp = reinterpret_cast<const float4*>(Bv + p * N + G * 8);
    float4 b0 = bp[0], b1 = bp[1];
    float bl[8] = {b0.x,b0.y,b0.z,b0.w,b1.x,b1.y,b1.z,b1.w};
    #pragma unroll
    for (int r = 0; r < 8; ++r) {
      float s = 0.f;
      #pragma unroll
      for (int q = 0; q < 4; ++q) {
        s = fmaf(A2[r][q].x, A2[r][q].x, s);
        s = fmaf(A2[r][q].y, A2[r][q].y, s);
      }
      s = red32s(s);
      float inv = 1.0f / fmaxf(sqrtf(s), 1e-12f);
      #pragma unroll
      for (int q = 0; q < 4; ++q) A2[r][q] *= inv;   // elementwise, bitwise == r8
      btl32[r] = (bl[r] * inv - 1e-3f) * -0.03125f;  // -(b_w - MU)/32, exact scale
    }
  }

  // ---- helpers (packed matvecs) ----
  auto fwd8 = [&](const v2f (&vv)[4], float (&s)[8]) {   // s[r] = full (A vv)[G*8+r]
    #pragma unroll
    for (int r = 0; r < 8; ++r) {
      v2f acc = A2[r][0] * vv[0];
      #pragma unroll
      for (int q = 1; q < 4; ++q) acc += A2[r][q] * vv[q];  // v_pk_fma_f32
      s[r] = acc.x + acc.y;
    }
    #pragma unroll
    for (int r = 0; r < 8; ++r) s[r] = red32s(s[r]);
  };
  auto fwd8_bt = [&](const v2f (&vv)[4], float (&s)[8]) { // + fused -b_tight
    #pragma unroll
    for (int r = 0; r < 8; ++r) {
      v2f acc = A2[r][0] * vv[0];
      #pragma unroll
      for (int q = 1; q < 4; ++q) acc += A2[r][q] * vv[q];
      s[r] = (acc.x + acc.y) + btl32[r];
    }
    #pragma unroll
    for (int r = 0; r < 8; ++r) s[r] = red32s(s[r]);
  };
  // in-lane A^T partial (r-ascending per col: BITWISE == r8); rotated b128 stores
  auto trans_write = [&](const float (&rr)[8]) {
    v2f gp[4];
    #pragma unroll
    for (int q = 0; q < 4; ++q) gp[q] = A2[0][q] * rr[0];
    #pragma unroll
    for (int r = 1; r < 8; ++r) {
      #pragma unroll
      for (int q = 0; q < 4; ++q) gp[q] += A2[r][q] * rr[r];  // v_pk_fma_f32
    }
    float* base = &part[(G << 8) + (((j ^ G) & 31) << 3)];
    *reinterpret_cast<float4*>(base + rot)       = make_float4(gp[0].x, gp[0].y, gp[1].x, gp[1].y);
    *reinterpret_cast<float4*>(base + (rot ^ 4)) = make_float4(gp[2].x, gp[2].y, gp[3].x, gp[3].y);
  };
  auto col_reduce = [&]() {  // 8 b32 reads + 2 quad_perm folds (r8-proven)
    float g = 0.f;
    #pragma unroll
    for (int i = 0; i < 8; ++i) {
      const int grp = h4 + 4 * i;
      g += part[(grp << 8) + (((chnk ^ grp) & 31) << 3) + coffR];
    }
    g += dppmv<0xB1>(g);   // fold lane^1
    g += dppmv<0x4E>(g);   // fold lane^2
    return g;
  };
  // 8 conflict-free b32 reads into col-pairs (same addresses as r8)
  auto load8v = [&](const float* base, v2f (&d)[4]) {
    #pragma unroll
    for (int q = 0; q < 4; ++q) {
      d[q].x = base[(2 * q)     * TPAD + j];
      d[q].y = base[(2 * q + 1) * TPAD + j];
    }
  };

  // ---- power iteration, DEFERRED NORMALIZATION (proven r7/r8) ----
  v2f vloc[4];
  #pragma unroll
  for (int q = 0; q < 4; ++q) vloc[q] = (v2f){0.0625f, 0.0625f};

  for (int pit = 0; pit < 5; ++pit) {
    float av[8];
    fwd8(vloc, av);
    trans_write(av);
    __syncthreads();
    float g = col_reduce();                 // (AtA u)[c_red], unnormalized
    if (h4 == 0) gn[cT] = g;
    __syncthreads();
    load8v(gn, vloc);                       // u <- AtA u
  }
  // eta = V2/(S + rho*V2), V2=||u||^2, S=sum((A u)^2)
  {
    float av[8];
    fwd8(vloc, av);
    float ssa = 0.f;
    #pragma unroll
    for (int r = 0; r < 8; ++r) ssa = fmaf(av[r], av[r], ssa);  // group-uniform
    ssa += __shfl_xor(ssa, 32);
    if (lane == 0) wsc[w] = ssa;
    if (t < 32) {                      // group 0: j=t, cols t*8..+7 (c-order kept)
      float sv = 0.f;
      #pragma unroll
      for (int q = 0; q < 4; ++q) {
        sv = fmaf(vloc[q].x, vloc[q].x, sv);
        sv = fmaf(vloc[q].y, vloc[q].y, sv);
      }
      sv = red32s(sv);
      if (t == 0) wsc2[0] = sv;
    }
    __syncthreads();
    if (t == 0) {
      float S = 0.f;
      #pragma unroll
      for (int i = 0; i < 16; ++i) S += wsc[i];
      float V2 = wsc2[0];
      scal[1] = V2 / (S + 1e-12f * V2);
    }
    __syncthreads();
  }
  const float eta = scal[1];

  // ---- UVP: 30 iterations, 2 barriers each ----
  v2f xloc[4];
  load8v(xn, xloc);
  float xred = xn[cT];
  #pragma unroll 1
  for (int k = 0; k < 30; ++k) {
    float s[8];
    fwd8_bt(xloc, s);                        // s = Ax - b_tight (fused)
    float rl[8];
    #pragma unroll
    for (int r = 0; r < 8; ++r) rl[r] = fmaxf(s[r], 0.f);
    trans_write(rl);
    __syncthreads();
    float g = col_reduce();
    xred = fmaf(-eta, g, xred);
    if (h4 == 0) xn[cT] = xred;
    __syncthreads();
    load8v(xn, xloc);
  }

  // ---- stage 2: gate + alpha ----
  v2f x0loc[4], dloc[4];
  load8v(x0n, x0loc);
  #pragma unroll
  for (int q = 0; q < 4; ++q) dloc[q] = x0loc[q] - xloc[q];
  float sx[8], sd[8];
  fwd8(xloc, sx);
  fwd8(dloc, sd);
  float mv = -INFINITY, aim = INFINITY;
  #pragma unroll
  for (int r = 0; r < 8; ++r) {
    float bw = fmaf(-32.f, btl32[r], 1e-3f);  // recover b_w exactly
    float ax = sx[r], ad = sd[r];
    mv = fmaxf(mv, ax - bw);
    float ai = (ad > 0.f) ? (bw - ax) / (ad + 1e-12f) : INFINITY;
    aim = fminf(aim, ai);
  }
  mv  = fmaxf(mv,  __shfl_xor(mv, 32));
  aim = fminf(aim, __shfl_xor(aim, 32));
  if (lane == 0) { wsc[w] = mv; wsc2[w] = aim; }
  __syncthreads();
  if (t == 0) {
    float M = -INFINITY, Al = INFINITY;
    #pragma unroll
    for (int i = 0; i < 16; ++i) { M = fmaxf(M, wsc[i]); Al = fminf(Al, wsc2[i]); }
    if (!isfinite(Al)) Al = 1.0f;
    Al = fminf(fmaxf(Al - 1e-6f, 0.f), 1.0f);
    scal[2] = M; scal[3] = Al;
  }
  __syncthreads();
  if (t < N) {
    float xv = xn[tT];
    float d  = x0n[tT] - xv;
    out[p * N + t] = (scal[2] <= 1e-7f) ? fmaf(scal[3], d, xv) : xv;
  }
}

extern "C" void kernel_launch(void* const* d_in, const int* in_sizes, int n_in,
                              void* d_out, int out_size, void* d_ws, size_t ws_size,
                              hipStream_t stream) {
  const float* X  = (const float*)d_in[0];
  const float* A  = (const float*)d_in[1];
  const float* Bv = (const float*)d_in[2];
  float* out = (float*)d_out;
  const int nprob = in_sizes[0] / N;   // 512
  icvp_kernel<<<nprob, 1024, 0, stream>>>(X, A, Bv, out);
}